// Round 1
// baseline (1167.251 us; speedup 1.0000x reference)
//
#include <hip/hip_runtime.h>
#include <hip/hip_bf16.h>

// FFT-based causal long convolution for (b=4, l=8192, d=1024) fp32.
// One workgroup per (b, d) pair. Real FFT of N=16384 done as complex FFT of
// M=8192 via even/odd packing; 64 KB LDS holds the whole sequence.
// Forward = radix-2 DIF (natural in -> bit-reversed out), inverse = radix-2
// DIT (bit-reversed in -> natural out) => no bit-reversal permutation pass.

#define M 8192            // complex FFT size
#define LOGM 13
#define NTH 256
#define MAXP 17           // ceil((M/2+1)/NTH)

__device__ __forceinline__ float2 cadd(float2 a, float2 b){ return make_float2(a.x+b.x, a.y+b.y); }
__device__ __forceinline__ float2 csub(float2 a, float2 b){ return make_float2(a.x-b.x, a.y-b.y); }
__device__ __forceinline__ float2 cmul(float2 a, float2 b){ return make_float2(a.x*b.x - a.y*b.y, a.x*b.y + a.y*b.x); }
__device__ __forceinline__ float2 conjf2(float2 a){ return make_float2(a.x, -a.y); }

__device__ __forceinline__ int rev13(int k){ return (int)(__brev((unsigned)k) >> 19); }

static __device__ const float PI_F = 3.14159265358979323846f;

// Forward radix-2 DIF: natural-order input, bit-reversed output.
__device__ __forceinline__ void fft_dif(float2* L, int tid) {
  for (int half = M/2; half >= 1; half >>= 1) {
    float astep = -PI_F / (float)half;
    for (int idx = tid; idx < M/2; idx += NTH) {
      int j  = idx & (half - 1);
      int i0 = 2*idx - j;          // blk*2*half + j
      int i1 = i0 + half;
      float2 a = L[i0], b = L[i1];
      float s, c;
      __sincosf((float)j * astep, &s, &c);
      float2 w = make_float2(c, s);          // e^{-i*pi*j/half}
      L[i0] = cadd(a, b);
      L[i1] = cmul(csub(a, b), w);
    }
    __syncthreads();
  }
}

// Inverse radix-2 DIT: bit-reversed input, natural output. Unscaled (no 1/M).
__device__ __forceinline__ void fft_dit_inv(float2* L, int tid) {
  for (int half = 1; half <= M/2; half <<= 1) {
    float astep = PI_F / (float)half;
    for (int idx = tid; idx < M/2; idx += NTH) {
      int j  = idx & (half - 1);
      int i0 = 2*idx - j;
      int i1 = i0 + half;
      float s, c;
      __sincosf((float)j * astep, &s, &c);
      float2 w = make_float2(c, s);          // e^{+i*pi*j/half}
      float2 a = L[i0];
      float2 b = cmul(L[i1], w);
      L[i0] = cadd(a, b);
      L[i1] = csub(a, b);
    }
    __syncthreads();
  }
}

__global__ __launch_bounds__(NTH, 2)
void longconv_fft_kernel(const float* __restrict__ x,
                         const float* __restrict__ filt,
                         float* __restrict__ y,
                         int B) {
  __shared__ float2 L[M];                    // 64 KB
  const int tid = threadIdx.x;
  const int blk = blockIdx.x;
  const int d = blk & 1023;                  // fastest dim: L2/L3 line reuse across blocks
  const int b = blk >> 10;

  // ---------------- Phase A: filter FFT ----------------
  const float* fp = filt + (size_t)d * 8192;
  for (int m = tid; m < M; m += NTH) {
    float2 v = make_float2(0.f, 0.f);
    if (m < M/2) { v.x = fp[2*m]; v.y = fp[2*m + 1]; }   // pack pairs; zero-pad tail
    L[m] = v;
  }
  __syncthreads();
  fft_dif(L, tid);

  // Unpack this thread's K_f pairs into registers.
  float2 Kk[MAXP], Kmk[MAXP];
#pragma unroll
  for (int p = 0; p < MAXP; ++p) {
    int k = tid + p * NTH;
    if (k <= M/2) {
      int rk  = rev13(k);
      int rmk = rev13((M - k) & (M - 1));    // Z[M] == Z[0]
      float2 Zk = L[rk], Zmk = L[rmk];
      float2 Ze = make_float2(0.5f*(Zk.x + Zmk.x), 0.5f*(Zk.y - Zmk.y)); // (Zk+conj(Zmk))/2
      float2 t  = make_float2(Zk.x - Zmk.x, Zk.y + Zmk.y);               // Zk-conj(Zmk)
      float2 Zo = make_float2(0.5f*t.y, -0.5f*t.x);                      // t/(2i)
      float s, c; __sincosf(-PI_F * (float)k * (1.0f/(float)M), &s, &c);
      float2 W = make_float2(c, s);                                      // e^{-i*pi*k/M}
      float2 WZo = cmul(W, Zo);
      Kk[p]  = cadd(Ze, WZo);                 // K[k]
      Kmk[p] = conjf2(csub(Ze, WZo));         // K[M-k]
    }
  }
  __syncthreads();                            // all reads of L done before reuse

  // ---------------- Phase B: signal FFT ----------------
  const float* xp = x + (size_t)b * 8192 * 1024 + d;
  for (int m = tid; m < M; m += NTH) {
    float2 v = make_float2(0.f, 0.f);
    if (m < M/2) {
      v.x = xp[(size_t)(2*m)     * 1024];
      v.y = xp[(size_t)(2*m + 1) * 1024];
    }
    L[m] = v;
  }
  __syncthreads();
  fft_dif(L, tid);

  // ---------------- Phase C: unpack * K, repack (in place, pairwise) ----------------
#pragma unroll
  for (int p = 0; p < MAXP; ++p) {
    int k = tid + p * NTH;
    if (k <= M/2) {
      int rk  = rev13(k);
      int rmk = rev13((M - k) & (M - 1));
      float2 Zk = L[rk], Zmk = L[rmk];
      float2 Ze = make_float2(0.5f*(Zk.x + Zmk.x), 0.5f*(Zk.y - Zmk.y));
      float2 t  = make_float2(Zk.x - Zmk.x, Zk.y + Zmk.y);
      float2 Zo = make_float2(0.5f*t.y, -0.5f*t.x);
      float s, c; __sincosf(-PI_F * (float)k * (1.0f/(float)M), &s, &c);
      float2 W = make_float2(c, s);
      float2 WZo = cmul(W, Zo);
      float2 Uk  = cadd(Ze, WZo);             // U[k]
      float2 Umk = conjf2(csub(Ze, WZo));     // U[M-k]
      float2 Yk  = cmul(Uk,  Kk[p]);
      float2 Ymk = cmul(Umk, Kmk[p]);
      // Repack Y (rfft spectrum) into packed-complex spectrum Zy:
      // Ye  = (Yk + conj(Ymk))/2 ; Zoy = conj(W) * (Yk - conj(Ymk))/2
      float2 Ye  = make_float2(0.5f*(Yk.x + Ymk.x), 0.5f*(Yk.y - Ymk.y));
      float2 t2  = make_float2(0.5f*(Yk.x - Ymk.x), 0.5f*(Yk.y + Ymk.y));
      float2 Zoy = cmul(conjf2(W), t2);
      // Zy[k] = Ye + i*Zoy ; Zy[M-k] = conj(Ye) + i*conj(Zoy)
      float2 Zyk  = make_float2(Ye.x - Zoy.y, Ye.y + Zoy.x);
      float2 Zymk = make_float2(Ye.x + Zoy.y, Zoy.x - Ye.y);
      L[rk]  = Zyk;
      L[rmk] = Zymk;                          // k==0 / k==M/2: same slot, same value
    }
  }
  __syncthreads();

  // ---------------- Phase D: inverse FFT ----------------
  fft_dit_inv(L, tid);

  // ---------------- Phase E: write first l=8192 samples, scaled by 1/M ----------------
  float* yp = y + (size_t)b * 8192 * 1024 + d;
  const float inv = 1.0f / (float)M;
  for (int m = tid; m < M/2; m += NTH) {
    yp[(size_t)(2*m)     * 1024] = L[m].x * inv;
    yp[(size_t)(2*m + 1) * 1024] = L[m].y * inv;
  }
}

extern "C" void kernel_launch(void* const* d_in, const int* in_sizes, int n_in,
                              void* d_out, int out_size, void* d_ws, size_t ws_size,
                              hipStream_t stream) {
  const float* x    = (const float*)d_in[0];   // (b, l, d) fp32
  const float* filt = (const float*)d_in[1];   // (d, l) fp32
  float* y = (float*)d_out;                    // (b, l, d) fp32

  const int D = 1024, Lseq = 8192;
  const int B = in_sizes[0] / (D * Lseq);      // 4

  dim3 grid(B * D), block(NTH);
  hipLaunchKernelGGL(longconv_fft_kernel, grid, block, 0, stream, x, filt, y, B);
}